// Round 1
// 258.311 us; speedup vs baseline: 1.0577x; 1.0577x over previous
//
#include <hip/hip_runtime.h>

// MaskedSelfAttention: B=4, S=4096, D=1024, H=128. fp32 in/out, bf16 MFMA compute.
// v8: flash_attn rebuilt around UNIFORM work chunks + barrier-free main loop.
//  - (b,T) tile split into n(T)=ceil((T+1)/5) chunks of <=10 key-iters -> 476
//    uniform blocks (was 512 blocks of 1..16 iters; wall was the 16-iter ones,
//    avg occupancy 13.5% from the triangular drain).
//  - K and V MFMA A-fragments are loaded DIRECTLY from global (Kb row-major and
//    Vt[b][h][s] are exactly fragment layout; KV is 2MiB/batch -> L2-resident,
//    4-wave duplication L1-served). No Ks/Vs LDS, ZERO __syncthreads in the
//    main loop, no staging regs, bank conflicts only on the small plT buffer.
//  - merge handles up to 7 partials: j<2 stored in the tile's own out rows
//    (staged to regs before overwrite), j>=2 in pex.
// ws (20.3 MiB): Qb bf16[16384][128] | Kb | Vt bf16[4][128][4096]
//   | Wb bf16[384][1024] @12,582,912 (dead after qkv; ml f32[476][128][2]
//     overlays it) | pex bf16[240][128][128] @13,369,344 (end 21,233,664)

typedef __bf16 bf16x8 __attribute__((ext_vector_type(8)));
typedef __bf16 bf16x4 __attribute__((ext_vector_type(4)));
typedef __bf16 bf16x2 __attribute__((ext_vector_type(2)));
typedef float  f32x4  __attribute__((ext_vector_type(4)));

#define MFMA16(a, b, c) __builtin_amdgcn_mfma_f32_16x16x32_bf16(a, b, c, 0, 0, 0)
#define EXP2F(x) __builtin_amdgcn_exp2f(x)

// ---------------------------------------------------------------- prep_w ----
__global__ __launch_bounds__(256) void prep_w(
    const float* __restrict__ Wq, const float* __restrict__ Wk,
    const float* __restrict__ Wv, __bf16* __restrict__ Wb)
{
    int i = (blockIdx.x * 256 + threadIdx.x) * 4;
    int row = i >> 10;
    const float* W = (row < 128) ? Wq : (row < 256) ? Wk : Wv;
    float4 v = *(const float4*)&W[(size_t)(row & 127) * 1024 + (i & 1023)];
    bf16x4 pk = {(__bf16)v.x, (__bf16)v.y, (__bf16)v.z, (__bf16)v.w};
    *(bf16x4*)&Wb[i] = pk;
}

// -------------------------------------------------------------- qkv_gemm ----
// v8: 1-D grid, which = bx%3 so the 3 QKV blocks sharing an x slab are
// dispatch-adjacent (2nd/3rd slab reads hit L2/L3 instead of HBM).
// Otherwise v7: true LDS double-buffer, ONE barrier per K-iter. Block 64x128,
// 4 waves 2x2, wave 32x64 (2x4 MFMA 16x16x32), BK=64.
__global__ __launch_bounds__(256) void qkv_gemm(
    const float* __restrict__ x, const __bf16* __restrict__ Wb,
    const float* __restrict__ bq, const float* __restrict__ bk,
    const float* __restrict__ bv,
    __bf16* __restrict__ Qb, __bf16* __restrict__ Kb, __bf16* __restrict__ Vt)
{
    __shared__ __bf16 As[2][64][72];
    __shared__ __bf16 Bs[2][128][72];

    const int tid   = threadIdx.x;
    const int bx    = blockIdx.x;
    const int which = bx % 3;               // 0=Q 1=K 2=V
    const int m0    = (bx / 3) * 64;
    const int n0    = which * 128;
    const int lane = tid & 63, wid = tid >> 6;
    const int quad = lane >> 4, l16 = lane & 15;
    const int wm = (wid >> 1) * 32, wn = (wid & 1) * 64;

    const f32x4 fzero = {0.f, 0.f, 0.f, 0.f};
    f32x4 acc[2][4];
#pragma unroll
    for (int i = 0; i < 2; ++i)
#pragma unroll
        for (int j = 0; j < 4; ++j) acc[i][j] = fzero;

    const int arow = tid >> 2, ac = (tid & 3) * 16;   // A: 4 float4/thread
    const int brow = tid >> 1, bc = (tid & 1) * 32;   // B: 4 uint4/thread

    float4 ar[4];
    uint4  br[4];
    {
        const float* sa = &x[(size_t)(m0 + arow) * 1024 + ac];
#pragma unroll
        for (int q = 0; q < 4; ++q) ar[q] = *(const float4*)&sa[q * 4];
        const __bf16* sB = &Wb[(size_t)(n0 + brow) * 1024 + bc];
#pragma unroll
        for (int q = 0; q < 4; ++q) br[q] = *(const uint4*)&sB[q * 8];
    }

    for (int t = 0; t < 16; ++t) {
        const int buf = t & 1;
        {   // store staged regs (A: fp32 -> bf16)
            bf16x8 p0 = {(__bf16)ar[0].x, (__bf16)ar[0].y, (__bf16)ar[0].z, (__bf16)ar[0].w,
                         (__bf16)ar[1].x, (__bf16)ar[1].y, (__bf16)ar[1].z, (__bf16)ar[1].w};
            bf16x8 p1 = {(__bf16)ar[2].x, (__bf16)ar[2].y, (__bf16)ar[2].z, (__bf16)ar[2].w,
                         (__bf16)ar[3].x, (__bf16)ar[3].y, (__bf16)ar[3].z, (__bf16)ar[3].w};
            *(bf16x8*)&As[buf][arow][ac]     = p0;
            *(bf16x8*)&As[buf][arow][ac + 8] = p1;
#pragma unroll
            for (int q = 0; q < 4; ++q)
                *(uint4*)&Bs[buf][brow][bc + q * 8] = br[q];
        }
        __syncthreads();
        if (t < 15) {                       // prefetch t+1, consumed next iter
            const int kk = (t + 1) * 64;
            const float* sa = &x[(size_t)(m0 + arow) * 1024 + kk + ac];
#pragma unroll
            for (int q = 0; q < 4; ++q) ar[q] = *(const float4*)&sa[q * 4];
            const __bf16* sB = &Wb[(size_t)(n0 + brow) * 1024 + kk + bc];
#pragma unroll
            for (int q = 0; q < 4; ++q) br[q] = *(const uint4*)&sB[q * 8];
        }
#pragma unroll
        for (int ks = 0; ks < 2; ++ks) {
            const int k0 = ks * 32 + quad * 8;
            bf16x8 a[2], bb[4];
#pragma unroll
            for (int mt = 0; mt < 2; ++mt)
                a[mt] = *(const bf16x8*)&As[buf][wm + mt * 16 + l16][k0];
#pragma unroll
            for (int nt = 0; nt < 4; ++nt)
                bb[nt] = *(const bf16x8*)&Bs[buf][wn + nt * 16 + l16][k0];
#pragma unroll
            for (int mt = 0; mt < 2; ++mt)
#pragma unroll
                for (int nt = 0; nt < 4; ++nt)
                    acc[mt][nt] = MFMA16(a[mt], bb[nt], acc[mt][nt]);
        }
    }

    const float* bias = (which == 0) ? bq : (which == 1) ? bk : bv;
    if (which < 2) {
        __bf16* dst = (which == 0) ? Qb : Kb;
#pragma unroll
        for (int nt = 0; nt < 4; ++nt) {
            int col = wn + nt * 16 + l16;
            float bvv = bias[col];
#pragma unroll
            for (int mt = 0; mt < 2; ++mt)
#pragma unroll
                for (int r = 0; r < 4; ++r) {
                    int row = m0 + wm + mt * 16 + quad * 4 + r;
                    dst[(size_t)row * 128 + col] = (__bf16)(acc[mt][nt][r] + bvv);
                }
        }
    } else {
#pragma unroll
        for (int nt = 0; nt < 4; ++nt) {
            int col = wn + nt * 16 + l16;               // head index
            float bvv = bias[col];
#pragma unroll
            for (int mt = 0; mt < 2; ++mt) {
                int row = m0 + wm + mt * 16 + quad * 4;
                int bb_ = row >> 12, s = row & 4095;
                bf16x4 pk = {(__bf16)(acc[mt][nt][0] + bvv),
                             (__bf16)(acc[mt][nt][1] + bvv),
                             (__bf16)(acc[mt][nt][2] + bvv),
                             (__bf16)(acc[mt][nt][3] + bvv)};
                *(bf16x4*)&Vt[((size_t)(bb_ * 128 + col)) * 4096 + s] = pk;
            }
        }
    }
}

// -------------------------------------------------------------- flash_attn --
// v8: uniform chunks (<=10 key-iters), 476 blocks, NO barriers in the main
// loop. K/V fragments loaded directly from global (L2-resident); plT is the
// only main-loop LDS (per-wave, ordered by in-order DS + lgkmcnt). Computes
// S^T = K Q^T (softmax reduces over quads, 2 shfls), O^T = V^T P^T; epilogue
// transposes via LDS (overlaying plT) and stores coalesced bf16 partials:
// chunk j<2 -> the tile's own out rows, j>=2 -> pex; (m,l) in log2 domain.
__global__ __launch_bounds__(256, 2) void flash_attn(
    const __bf16* __restrict__ Qb, const __bf16* __restrict__ Kb,
    const __bf16* __restrict__ Vt, const int* __restrict__ mask,
    float* __restrict__ out, float* __restrict__ ml, __bf16* __restrict__ pex)
{
    __shared__ __align__(16) char smem[34816];
    __bf16 (*plT)[32][72] = (__bf16(*)[32][72])smem;   // [wave][q32][key64+pad]
    __bf16 (*OL)[136]     = (__bf16(*)[136])smem;      // epilogue overlay

    // ---- block -> (T, b, j): n(T)=ceil((T+1)/5) chunks of <=10 key-iters ----
    int ii = blockIdx.x, T = 0, n, cum = 0, cumex = 0;
    for (;; ++T) {
        n = (T + 5) / 5;
        if (ii < 4 * n) break;
        ii -= 4 * n;
        cum += n;                            // per-b slot prefix
        cumex += (n > 2) ? (n - 2) : 0;      // per-b pex prefix
    }
    const int b  = ii / n;
    const int j  = ii % n;
    const int nk = 2 * (T + 1);
    const int t0 = j * 10;
    const int t1 = (nk < t0 + 10) ? nk : (t0 + 10);
    const int r0 = T * 128;
    const int slot = b * 119 + cum + j;      // ml slot id (476 total)

    const int tid = threadIdx.x, wid = tid >> 6, lane = tid & 63;
    const int quad = lane >> 4, l16 = lane & 15;
    const int qw = r0 + wid * 32;                      // wave's q base
    const size_t sb = (size_t)b * 4096;
    const float qs = 0.08838834764831845f * 1.4426950408889634f; // scale*log2e

    bf16x8 qf[2][4];                                   // Q B-frags, scale folded
#pragma unroll
    for (int nf = 0; nf < 2; ++nf)
#pragma unroll
        for (int ks = 0; ks < 4; ++ks) {
            qf[nf][ks] = *(const bf16x8*)
                &Qb[(sb + qw + nf * 16 + l16) * 128 + ks * 32 + quad * 8];
#pragma unroll
            for (int e = 0; e < 8; ++e)
                qf[nf][ks][e] = (__bf16)((float)qf[nf][ks][e] * qs);
        }

    float mi[2] = {-1e30f, -1e30f}, li[2] = {0.f, 0.f};
    const f32x4 fzero = {0.f, 0.f, 0.f, 0.f};
    f32x4 o[8][2];                                     // O^T: 8 head-frags x 2 q-frags
#pragma unroll
    for (int hf = 0; hf < 8; ++hf)
#pragma unroll
        for (int nf = 0; nf < 2; ++nf) o[hf][nf] = fzero;

    // per-lane fragment base pointers (global = fragment layout)
    const __bf16* kb = Kb + (sb + l16) * 128 + quad * 8;
    const __bf16* vb = Vt + ((size_t)b * 128 + l16) * 4096 + quad * 8;

    for (int t = t0; t < t1; ++t) {
        const int k0 = t * 64;
        const int mv = mask[sb + k0 + lane];

        // ---- S^T = K Q^T: rows=keys(64, 4 mf), cols=q(32, 2 nf) ----
        f32x4 s[4][2];
#pragma unroll
        for (int mf = 0; mf < 4; ++mf)
#pragma unroll
            for (int nf = 0; nf < 2; ++nf) s[mf][nf] = fzero;
#pragma unroll
        for (int ks = 0; ks < 4; ++ks) {
            bf16x8 a[4];
#pragma unroll
            for (int mf = 0; mf < 4; ++mf)
                a[mf] = *(const bf16x8*)&kb[(size_t)(k0 + mf * 16) * 128 + ks * 32];
#pragma unroll
            for (int mf = 0; mf < 4; ++mf)
#pragma unroll
                for (int nf = 0; nf < 2; ++nf)
                    s[mf][nf] = MFMA16(a[mf], qf[nf][ks], s[mf][nf]);
        }
        // prefetch PV first half's V frags above the softmax (hides L2 latency)
        bf16x8 va0[8];
#pragma unroll
        for (int hf = 0; hf < 8; ++hf)
            va0[hf] = *(const bf16x8*)&vb[(size_t)(hf * 16) * 4096 + k0];

        // ---- masking (C-layout: key = mf*16+quad*4+r, q = qw+nf*16+l16) ----
        unsigned long long mb = __ballot(mv != 0);
        if (mb != ~0ull || k0 + 63 > qw) {
#pragma unroll
            for (int mf = 0; mf < 4; ++mf)
#pragma unroll
                for (int r = 0; r < 4; ++r) {
                    int kl = mf * 16 + quad * 4 + r;
                    bool mok = (mb >> kl) & 1;
                    int kc = k0 + kl;
#pragma unroll
                    for (int nf = 0; nf < 2; ++nf) {
                        int q = qw + nf * 16 + l16;
                        bool ok = mok && (kc <= q);
                        s[mf][nf][r] = ok ? s[mf][nf][r] : -1e30f;
                    }
                }
        }
        // ---- online softmax per q (log2 domain; reduce over quads) ----
#pragma unroll
        for (int nf = 0; nf < 2; ++nf) {
            float mx = s[0][nf][0];
#pragma unroll
            for (int mf = 0; mf < 4; ++mf)
#pragma unroll
                for (int r = 0; r < 4; ++r) mx = fmaxf(mx, s[mf][nf][r]);
            mx = fmaxf(mx, __shfl_xor(mx, 16));
            mx = fmaxf(mx, __shfl_xor(mx, 32));
            float mnew  = fmaxf(mi[nf], mx);
            float alpha = EXP2F(mi[nf] - mnew);
            float rs = 0.f;
#pragma unroll
            for (int mf = 0; mf < 4; ++mf)
#pragma unroll
                for (int r = 0; r < 4; ++r) {
                    float sv = s[mf][nf][r];
                    float p = (sv < -5e29f) ? 0.f : EXP2F(sv - mnew);
                    s[mf][nf][r] = p;
                    rs += p;
                }
            rs += __shfl_xor(rs, 16);
            rs += __shfl_xor(rs, 32);
            li[nf] = li[nf] * alpha + rs;
            mi[nf] = mnew;
#pragma unroll
            for (int hf = 0; hf < 8; ++hf) {
                o[hf][nf][0] *= alpha; o[hf][nf][1] *= alpha;
                o[hf][nf][2] *= alpha; o[hf][nf][3] *= alpha;
            }
            // pack P (consecutive keys in-lane) -> b32 LDS writes
            int ql = nf * 16 + l16;
#pragma unroll
            for (int mf = 0; mf < 4; ++mf) {
                bf16x2 w0 = {(__bf16)s[mf][nf][0], (__bf16)s[mf][nf][1]};
                bf16x2 w1 = {(__bf16)s[mf][nf][2], (__bf16)s[mf][nf][3]};
                *(bf16x2*)&plT[wid][ql][mf * 16 + quad * 4]     = w0;
                *(bf16x2*)&plT[wid][ql][mf * 16 + quad * 4 + 2] = w1;
            }
        }
        asm volatile("s_waitcnt lgkmcnt(0)" ::: "memory"); // per-wave DS order
        // ---- O^T += V^T P^T (V frags straight from global) ----
        bf16x8 pb0[2], pb1[2];
#pragma unroll
        for (int nf = 0; nf < 2; ++nf) {
            pb0[nf] = *(const bf16x8*)&plT[wid][nf * 16 + l16][quad * 8];
            pb1[nf] = *(const bf16x8*)&plT[wid][nf * 16 + l16][32 + quad * 8];
        }
        bf16x8 va1[8];
#pragma unroll
        for (int hf = 0; hf < 8; ++hf)
            va1[hf] = *(const bf16x8*)&vb[(size_t)(hf * 16) * 4096 + k0 + 32];
#pragma unroll
        for (int hf = 0; hf < 8; ++hf)
#pragma unroll
            for (int nf = 0; nf < 2; ++nf)
                o[hf][nf] = MFMA16(va0[hf], pb0[nf], o[hf][nf]);
#pragma unroll
        for (int hf = 0; hf < 8; ++hf)
#pragma unroll
            for (int nf = 0; nf < 2; ++nf)
                o[hf][nf] = MFMA16(va1[hf], pb1[nf], o[hf][nf]);
    }

    // ---- epilogue: transpose O^T via LDS, coalesced bf16 partial store ----
    __syncthreads();                                   // plT dead; OL overlays
    float inv[2];
#pragma unroll
    for (int nf = 0; nf < 2; ++nf) inv[nf] = (li[nf] > 0.f) ? 1.0f / li[nf] : 0.f;
#pragma unroll
    for (int nf = 0; nf < 2; ++nf) {
        int ql = wid * 32 + nf * 16 + l16;
#pragma unroll
        for (int hf = 0; hf < 8; ++hf) {
            int hd = hf * 16 + quad * 4;
            bf16x2 w0 = {(__bf16)(o[hf][nf][0] * inv[nf]), (__bf16)(o[hf][nf][1] * inv[nf])};
            bf16x2 w1 = {(__bf16)(o[hf][nf][2] * inv[nf]), (__bf16)(o[hf][nf][3] * inv[nf])};
            *(bf16x2*)&OL[ql][hd]     = w0;
            *(bf16x2*)&OL[ql][hd + 2] = w1;
        }
        if (quad == 0) {
            size_t base = ((size_t)slot * 128 + ql) * 2;
            ml[base]     = mi[nf];
            ml[base + 1] = li[nf];
        }
    }
    __syncthreads();
    __bf16* dst = (j < 2)
        ? (__bf16*)((char*)out + (sb + r0) * 512 + (size_t)j * 32768)
        : pex + ((size_t)(b * 60 + cumex + (j - 2))) * 16384;
    {
        int qrow = tid >> 1, cb2 = (tid & 1) * 64;
#pragma unroll
        for (int i = 0; i < 8; ++i) {
            bf16x8 v = *(const bf16x8*)&OL[qrow][cb2 + i * 8];
            *(bf16x8*)&dst[(size_t)qrow * 128 + cb2 + i * 8] = v;
        }
    }
}

// ----------------------------------------------------------------- mergeN ---
// One block per (b,T): combine n(T)<=7 pre-normalized bf16 partials (j<2 from
// the tile's own out rows, staged to regs before overwrite; j>=2 streamed from
// pex) into final fp32.
__global__ __launch_bounds__(256) void mergeN(
    float* __restrict__ out, const float* __restrict__ ml,
    const __bf16* __restrict__ pex)
{
    const int T = blockIdx.x, b = blockIdx.y;
    int cum = 0, cumex = 0;
    for (int tt = 0; tt < T; ++tt) {
        int nn = (tt + 5) / 5;
        cum += nn;
        cumex += (nn > 2) ? (nn - 2) : 0;
    }
    const int n  = (T + 5) / 5;
    const int r0 = T * 128;
    const size_t sb = (size_t)b * 4096;
    const int ql = threadIdx.x >> 1, ch = (threadIdx.x & 1) * 64;
    const int slot0 = b * 119 + cum;

    float mm = -1e30f;
    for (int jj = 0; jj < n; ++jj)
        mm = fmaxf(mm, ml[((size_t)(slot0 + jj) * 128 + ql) * 2]);

    // stage the (up to 2) in-out partials before overwriting out
    const __bf16* pout = (const __bf16*)((const char*)out + (sb + r0) * 512);
    bf16x8 rg0[8], rg1[8];
#pragma unroll
    for (int q2 = 0; q2 < 8; ++q2)
        rg0[q2] = *(const bf16x8*)&pout[(size_t)ql * 128 + ch + q2 * 8];
#pragma unroll
    for (int q2 = 0; q2 < 8; ++q2)
        rg1[q2] = *(const bf16x8*)&pout[16384 + (size_t)ql * 128 + ch + q2 * 8];
    __syncthreads();                                   // all reads done

    float acc[64];
#pragma unroll
    for (int k = 0; k < 64; ++k) acc[k] = 0.f;
    float den = 0.f;
    {   // j = 0 (always exists)
        size_t base = ((size_t)slot0 * 128 + ql) * 2;
        float m = ml[base], l = ml[base + 1];
        float w = (l > 0.f) ? EXP2F(m - mm) * l : 0.f;
        den += w;
#pragma unroll
        for (int q2 = 0; q2 < 8; ++q2)
#pragma unroll
            for (int e = 0; e < 8; ++e)
                acc[q2 * 8 + e] += w * (float)rg0[q2][e];
    }
    if (n > 1) {   // j = 1
        size_t base = ((size_t)(slot0 + 1) * 128 + ql) * 2;
        float m = ml[base], l = ml[base + 1];
        float w = (l > 0.f) ? EXP2F(m - mm) * l : 0.f;
        den += w;
#pragma unroll
        for (int q2 = 0; q2 < 8; ++q2)
#pragma unroll
            for (int e = 0; e < 8; ++e)
                acc[q2 * 8 + e] += w * (float)rg1[q2][e];
    }
    for (int jj = 2; jj < n; ++jj) {
        size_t base = ((size_t)(slot0 + jj) * 128 + ql) * 2;
        float m = ml[base], l = ml[base + 1];
        float w = (l > 0.f) ? EXP2F(m - mm) * l : 0.f;
        den += w;
        const __bf16* p = pex + ((size_t)(b * 60 + cumex + (jj - 2))) * 16384
                        + (size_t)ql * 128 + ch;
#pragma unroll
        for (int q2 = 0; q2 < 8; ++q2) {
            bf16x8 v = *(const bf16x8*)&p[q2 * 8];
#pragma unroll
            for (int e = 0; e < 8; ++e)
                acc[q2 * 8 + e] += w * (float)v[e];
        }
    }
    float sc = (den > 0.f) ? 1.0f / den : 0.f;
    float* op = &out[(sb + r0 + ql) * 128 + ch];
#pragma unroll
    for (int q2 = 0; q2 < 8; ++q2) {
        float4 v0 = {acc[q2 * 8 + 0] * sc, acc[q2 * 8 + 1] * sc,
                     acc[q2 * 8 + 2] * sc, acc[q2 * 8 + 3] * sc};
        float4 v1 = {acc[q2 * 8 + 4] * sc, acc[q2 * 8 + 5] * sc,
                     acc[q2 * 8 + 6] * sc, acc[q2 * 8 + 7] * sc};
        *(float4*)&op[q2 * 8]     = v0;
        *(float4*)&op[q2 * 8 + 4] = v1;
    }
}

// ----------------------------------------------------------------- launch ---
extern "C" void kernel_launch(void* const* d_in, const int* in_sizes, int n_in,
                              void* d_out, int out_size, void* d_ws, size_t ws_size,
                              hipStream_t stream)
{
    const float* x    = (const float*)d_in[0];
    const int*   mask = (const int*)d_in[1];
    const float* Wq   = (const float*)d_in[2];
    const float* bq   = (const float*)d_in[3];
    const float* Wk   = (const float*)d_in[4];
    const float* bk   = (const float*)d_in[5];
    const float* Wv   = (const float*)d_in[6];
    const float* bv   = (const float*)d_in[7];
    float* out = (float*)d_out;

    char* ws = (char*)d_ws;
    __bf16* Qb  = (__bf16*)ws;                        // 4 MiB
    __bf16* Kb  = Qb + (size_t)16384 * 128;           // 4 MiB
    __bf16* Vt  = Kb + (size_t)16384 * 128;           // 4 MiB ([b][h][s])
    __bf16* Wb  = Vt + (size_t)16384 * 128;           // 768 KiB @ 12,582,912
    float*  ml  = (float*)(ws + 12582912);            // 476 KiB, overlays dead Wb
    __bf16* pex = (__bf16*)(ws + 13369344);           // 7.5 MiB (j>=2 partials)

    prep_w<<<384, 256, 0, stream>>>(Wq, Wk, Wv, Wb);
    qkv_gemm<<<768, 256, 0, stream>>>(x, Wb, bq, bk, bv, Qb, Kb, Vt);
    flash_attn<<<476, 256, 0, stream>>>(Qb, Kb, Vt, mask, out, ml, pex);
    mergeN<<<dim3(32, 4), 256, 0, stream>>>(out, ml, pex);
}